// Round 4
// baseline (194.744 us; speedup 1.0000x reference)
//
#include <hip/hip_runtime.h>

typedef __attribute__((ext_vector_type(8))) short short8;
typedef __attribute__((ext_vector_type(4))) float f32x4;
typedef unsigned short u16;
typedef unsigned int u32;
typedef unsigned long long u64;

#define XH 114
#define XW 114
#define CINC 64
#define COUT 128
#define OH 112
#define OW 112
#define NB 32
#define KTOT 576   // CIN*9

static __device__ __forceinline__ u16 f2bf(float f) {
    u32 x = __float_as_uint(f);
    u32 r = (x + 0x7fffu + ((x >> 16) & 1u)) >> 16;
    return (u16)r;
}

#define MFMA16(a, b, c) __builtin_amdgcn_mfma_f32_16x16x32_bf16((a), (b), (c), 0, 0, 0)

// ---------------- fast path ----------------

// weights -> bf16, K reordered to (kh,kw,ci):  wbf[o][(kh*3+kw)*64 + ci]
__global__ __launch_bounds__(256) void wcvt_reord(const float* __restrict__ w,
                                                  u16* __restrict__ wbf) {
    int i = blockIdx.x * 256 + threadIdx.x;   // 73728 total, exact
    int o = i / KTOT;
    int rem = i - o * KTOT;
    int khkw = rem >> 6;        // 0..8
    int ci = rem & 63;
    wbf[i] = f2bf(w[(o * CINC + ci) * 9 + khkw]);
}

// Fused implicit-GEMM conv: block = (b, row-pair), 512 thr = 8 waves
// (2 cout-groups of 64) x (2 rows) x (2 n-halves). Staging reads NCHW f32
// directly, converts to bf16, writes swizzled [pix][ci] LDS. No xcvt pass.
__global__ __launch_bounds__(512, 4) void conv_fused(const float* __restrict__ x,
                                                     const u16* __restrict__ wbf,
                                                     const float* __restrict__ bias,
                                                     float* __restrict__ out) {
    __shared__ u16 ldsB[4 * XW * CINC];   // 58368 B: [pix=r*114+w][ci], slot-swizzled
    char* ldsc = (char*)ldsB;

    const int tid = threadIdx.x;
    int bid = blockIdx.x;
    { // bijective XCD swizzle: 1792 = 8*224; each XCD owns 4 whole batches
        int xcd = bid & 7;
        bid = xcd * 224 + (bid >> 3);
    }
    const int b  = bid / 56;
    const int h0 = (bid - b * 56) * 2;

    // ---- fused staging: 256 segments = 4 rows x 64 ci, 2 threads/segment ----
    {
        const int seg  = tid >> 1;        // 0..255
        const int half = tid & 1;         // w-half: 0 -> w 0..57, 1 -> w 56..113
        const int r    = seg >> 6;        // input row 0..3
        const int ci   = seg & 63;
        const float* srcrow = x + ((size_t)(b * CINC + ci) * XH + (h0 + r)) * XW + half * 56;
        const int pixbase = r * XW + half * 56;
        const int cilo = (ci & 7) << 1;
        const int slot = ci >> 3;
        #pragma unroll
        for (int i = 0; i < 29; ++i) {
            float2 v = *(const float2*)(srcrow + 2 * i);   // 8B-aligned
            const int p0 = pixbase + 2 * i;
            const int p1 = p0 + 1;
            *(u16*)(ldsc + ((p0 << 7) | ((slot ^ (p0 & 7)) << 4) | cilo)) = f2bf(v.x);
            *(u16*)(ldsc + ((p1 << 7) | ((slot ^ (p1 & 7)) << 4) | cilo)) = f2bf(v.y);
        }
    }
    __syncthreads();

    const int lane = tid & 63;
    const int wv   = tid >> 6;        // 0..7
    const int l16  = lane & 15;
    const int lhi  = lane >> 4;
    const int wm   = wv >> 2;         // cout group: couts [wm*64, wm*64+64)
    const int wn   = (wv >> 1) & 1;   // row within pair
    const int ns   = wv & 1;          // n-half: 0 -> nf 0..3 (pix 0..63), 1 -> nf 0..2 (pix 64..111)
    const int nfn  = 4 - ns;

    const u16* wrow = wbf + (wm * 64 + l16) * KTOT + lhi * 8;

    f32x4 acc[4][4];
    const f32x4 zero = {0.f, 0.f, 0.f, 0.f};
    #pragma unroll
    for (int i = 0; i < 4; ++i)
        #pragma unroll
        for (int j = 0; j < 4; ++j) acc[i][j] = zero;

    // A-frag software pipeline: tsteps t=0..17 (t = khkw*2 + ch), unroll-by-2
    short8 aA0 = *(const short8*)(wrow);
    short8 aA1 = *(const short8*)(wrow + 16 * KTOT);
    short8 aA2 = *(const short8*)(wrow + 32 * KTOT);
    short8 aA3 = *(const short8*)(wrow + 48 * KTOT);
    short8 aB0, aB1, aB2, aB3;

    #pragma unroll 1
    for (int tt = 0; tt < 9; ++tt) {
        const int t0 = 2 * tt;
        // prefetch odd tstep's A (same khkw, ch=1)
        aB0 = *(const short8*)(wrow + (t0 + 1) * 32);
        aB1 = *(const short8*)(wrow + 16 * KTOT + (t0 + 1) * 32);
        aB2 = *(const short8*)(wrow + 32 * KTOT + (t0 + 1) * 32);
        aB3 = *(const short8*)(wrow + 48 * KTOT + (t0 + 1) * 32);

        const int kh = tt / 3;
        const int kw = tt - kh * 3;
        const int pix0 = (wn + kh) * XW + kw + ns * 64 + l16;

        { // compute t0 (ch=0): ci slot base lhi
            #pragma unroll
            for (int nf = 0; nf < 4; ++nf) {
                if (nf >= nfn) break;
                const int pix = pix0 + nf * 16;
                const int baddr = (pix << 7) + ((lhi ^ (pix & 7)) << 4);
                short8 bf = *(const short8*)(ldsc + baddr);
                acc[0][nf] = MFMA16(aA0, bf, acc[0][nf]);
                acc[1][nf] = MFMA16(aA1, bf, acc[1][nf]);
                acc[2][nf] = MFMA16(aA2, bf, acc[2][nf]);
                acc[3][nf] = MFMA16(aA3, bf, acc[3][nf]);
            }
        }
        // prefetch next even tstep's A
        if (tt < 8) {
            aA0 = *(const short8*)(wrow + (t0 + 2) * 32);
            aA1 = *(const short8*)(wrow + 16 * KTOT + (t0 + 2) * 32);
            aA2 = *(const short8*)(wrow + 32 * KTOT + (t0 + 2) * 32);
            aA3 = *(const short8*)(wrow + 48 * KTOT + (t0 + 2) * 32);
        }
        { // compute t1 = t0+1 (ch=1): ci slot base 4+lhi
            #pragma unroll
            for (int nf = 0; nf < 4; ++nf) {
                if (nf >= nfn) break;
                const int pix = pix0 + nf * 16;
                const int baddr = (pix << 7) + (((4 + lhi) ^ (pix & 7)) << 4);
                short8 bf = *(const short8*)(ldsc + baddr);
                acc[0][nf] = MFMA16(aB0, bf, acc[0][nf]);
                acc[1][nf] = MFMA16(aB1, bf, acc[1][nf]);
                acc[2][nf] = MFMA16(aB2, bf, acc[2][nf]);
                acc[3][nf] = MFMA16(aB3, bf, acc[3][nf]);
            }
        }
    }

    // ---- epilogue: C/D col=lane&15, row=(lane>>4)*4+j ----
    float* outb = out + (size_t)b * COUT * (OH * OW) + (h0 + wn) * OW + ns * 64;
    #pragma unroll
    for (int mf = 0; mf < 4; ++mf) {
        #pragma unroll
        for (int j = 0; j < 4; ++j) {
            const int o = wm * 64 + mf * 16 + lhi * 4 + j;
            const float bv = bias[o];
            #pragma unroll
            for (int nf = 0; nf < 4; ++nf) {
                if (nf >= nfn) break;
                outb[(size_t)o * (OH * OW) + nf * 16 + l16] = acc[mf][nf][j] + bv;
            }
        }
    }
}

// ---------------- fallback (R0 kernel, needs only 147456 B ws) ----------------

#define BK 32
#define NSTEP 18
#define LDB 40

__global__ __launch_bounds__(256) void wcvt_ident(const float* __restrict__ w,
                                                  u16* __restrict__ wbf) {
    int i = blockIdx.x * 256 + threadIdx.x;
    if (i < COUT * KTOT) wbf[i] = f2bf(w[i]);
}

__global__ __launch_bounds__(256) void conv_fb(const float* __restrict__ x,
                                               const u16* __restrict__ wbf,
                                               const float* __restrict__ bias,
                                               float* __restrict__ out) {
    __shared__ u16 ldsB[OW * LDB];
    const int tid = threadIdx.x;
    int bid = blockIdx.x;
    { int xcd = bid & 7; bid = xcd * 448 + (bid >> 3); }
    const int b = bid / OH;
    const int h = bid - b * OH;
    const float* xbp = x + (size_t)b * (CINC * XH * XW);
    float* outb = out + (size_t)b * (COUT * OH * OW) + h * OW;
    const int lane = tid & 63, wv = tid >> 6, l16 = lane & 15, lhi = lane >> 4;
    const int m0 = wv * 32;
    const int sk = tid >> 3, sn0 = (tid & 7) * 14;
    f32x4 acc[2][7];
    const f32x4 zero = {0.f, 0.f, 0.f, 0.f};
    #pragma unroll
    for (int i = 0; i < 2; ++i)
        #pragma unroll
        for (int j = 0; j < 7; ++j) acc[i][j] = zero;
    for (int t = 0; t < NSTEP; ++t) {
        const int kg = t * BK + sk;
        const int ci = kg / 9;
        const int r9 = kg - ci * 9;
        const int kh = r9 / 3, kw = r9 - (r9 / 3) * 3;
        const float* src = xbp + ((size_t)ci * XH + (h + kh)) * XW + kw + sn0;
        __syncthreads();
        #pragma unroll
        for (int i = 0; i < 14; ++i) ldsB[(sn0 + i) * LDB + sk] = f2bf(src[i]);
        __syncthreads();
        short8 afrag[2];
        #pragma unroll
        for (int mf = 0; mf < 2; ++mf)
            afrag[mf] = *(const short8*)(wbf + (m0 + mf * 16 + l16) * KTOT + t * BK + lhi * 8);
        #pragma unroll
        for (int nf = 0; nf < 7; ++nf) {
            short8 bfrag = *(const short8*)&ldsB[(nf * 16 + l16) * LDB + lhi * 8];
            acc[0][nf] = MFMA16(afrag[0], bfrag, acc[0][nf]);
            acc[1][nf] = MFMA16(afrag[1], bfrag, acc[1][nf]);
        }
    }
    #pragma unroll
    for (int mf = 0; mf < 2; ++mf)
        #pragma unroll
        for (int j = 0; j < 4; ++j) {
            const int o = m0 + mf * 16 + lhi * 4 + j;
            const float bv = bias[o];
            #pragma unroll
            for (int nf = 0; nf < 7; ++nf)
                outb[(size_t)o * (OH * OW) + nf * 16 + l16] = acc[mf][nf][j] + bv;
        }
}

extern "C" void kernel_launch(void* const* d_in, const int* in_sizes, int n_in,
                              void* d_out, int out_size, void* d_ws, size_t ws_size,
                              hipStream_t stream) {
    const float* x    = (const float*)d_in[0];
    const float* w    = (const float*)d_in[3];
    const float* bias = (const float*)d_in[4];
    float* out = (float*)d_out;

    const size_t WBYTES = (size_t)COUT * KTOT * 2;   // 147456
    if (ws_size >= WBYTES) {
        u16* wbf = (u16*)d_ws;
        wcvt_reord<<<(COUT * KTOT) / 256, 256, 0, stream>>>(w, wbf);
        conv_fused<<<NB * 56, 512, 0, stream>>>(x, wbf, bias, out);
    } else {
        u16* wbf = (u16*)d_ws;
        wcvt_ident<<<(COUT * KTOT + 255) / 256, 256, 0, stream>>>(w, wbf);
        conv_fb<<<NB * OH, 256, 0, stream>>>(x, wbf, bias, out);
    }
}

// Round 5
// 179.497 us; speedup vs baseline: 1.0849x; 1.0849x over previous
//
#include <hip/hip_runtime.h>

typedef __attribute__((ext_vector_type(8))) short short8;
typedef __attribute__((ext_vector_type(4))) float f32x4;
typedef __attribute__((ext_vector_type(4))) unsigned int u32x4;
typedef unsigned short u16;
typedef unsigned int u32;
typedef unsigned long long u64;

#define XH 114
#define XW 114
#define CINC 64
#define COUT 128
#define OH 112
#define OW 112
#define NB 32
#define KTOT 576   // CIN*9

static __device__ __forceinline__ u16 f2bf(float f) {
    u32 x = __float_as_uint(f);
    u32 r = (x + 0x7fffu + ((x >> 16) & 1u)) >> 16;
    return (u16)r;
}

#define MFMA16(a, b, c) __builtin_amdgcn_mfma_f32_16x16x32_bf16((a), (b), (c), 0, 0, 0)

static __device__ __forceinline__ void gload16(const void* g, void* l) {
    __builtin_amdgcn_global_load_lds(
        (const __attribute__((address_space(1))) unsigned int*)g,
        (__attribute__((address_space(3))) unsigned int*)l, 16, 0, 0);
}

// ---------------- fast path ----------------

// weights -> bf16, K reordered to (kh,kw,ci):  wbf[o][(kh*3+kw)*64 + ci]
__global__ __launch_bounds__(256) void wcvt_reord(const float* __restrict__ w,
                                                  u16* __restrict__ wbf) {
    int i = blockIdx.x * 256 + threadIdx.x;   // 73728 total, exact
    int o = i / KTOT;
    int rem = i - o * KTOT;
    int khkw = rem >> 6;        // 0..8
    int ci = rem & 63;
    wbf[i] = f2bf(w[(o * CINC + ci) * 9 + khkw]);
}

// x (NCHW f32, padded) -> xb bf16 with slot-swizzle BAKED into global layout:
//   xb[(b*114+h)*7296 + w*64 + (c8 ^ ((2h+w)&7))*8 + e] = x[b][8*c8+e][h][w]
__global__ __launch_bounds__(256) void xcvt(const float* __restrict__ x,
                                            u16* __restrict__ xb) {
    __shared__ u16 tile[XW * 70];   // [w][ci], u16 row stride 70 (dword 35, coprime 32)
    const int blk = blockIdx.x;     // 32*114
    const int b = blk / XH;
    const int h = blk - b * XH;
    const int tid = threadIdx.x;

    // phase 1: 3648 tasks = 32 ci-pairs x 114 w; coalesced f32 reads, packed u32 writes
    #pragma unroll
    for (int it = 0; it < 15; ++it) {
        int idx = it * 256 + tid;
        if (idx < 32 * XW) {
            int cp = idx / XW;                  // 0..31
            int w_ = idx - cp * XW;
            const float* s0 = x + ((size_t)(b * CINC + 2 * cp) * XH + h) * XW + w_;
            float a = s0[0];
            float c = s0[XH * XW];
            u32 pk = (u32)f2bf(a) | ((u32)f2bf(c) << 16);
            *(u32*)&tile[w_ * 70 + 2 * cp] = pk;
        }
    }
    __syncthreads();

    // phase 2: 912 tasks = 114 w x 8 c8; 4x ds_read_b32 -> one 16B store at swizzled slot
    u16* dstrow = xb + (size_t)(b * XH + h) * (XW * CINC);
    #pragma unroll
    for (int p2 = 0; p2 < 4; ++p2) {
        int task = p2 * 256 + tid;
        if (task < XW * 8) {
            int w_ = task >> 3;
            int c8 = task & 7;
            const u32* s = (const u32*)&tile[w_ * 70 + c8 * 8];
            u32x4 v = {s[0], s[1], s[2], s[3]};
            int slot = c8 ^ ((2 * h + w_) & 7);
            *(u32x4*)(dstrow + w_ * CINC + slot * 8) = v;
        }
    }
}

// implicit-GEMM conv: block=(b,row-pair), 512 thr = 8 waves (2wm x 2wn x 2ns).
// Staging = pure linear global_load_lds (swizzle pre-baked in xb).
__global__ __launch_bounds__(512, 4) void conv_glds(const u16* __restrict__ xb,
                                                    const u16* __restrict__ wbf,
                                                    const float* __restrict__ bias,
                                                    float* __restrict__ out) {
    __shared__ u16 ldsB[4 * XW * CINC];   // 58368 B, linear copy of 4 xb rows
    char* ldsc = (char*)ldsB;

    const int tid = threadIdx.x;
    int bid = blockIdx.x;
    { // bijective XCD swizzle: 1792 = 8*224
        int xcd = bid & 7;
        bid = xcd * 224 + (bid >> 3);
    }
    const int b  = bid / 56;
    const int h0 = (bid - b * 56) * 2;

    const int lane = tid & 63;
    const int wv   = tid >> 6;        // 0..7

    // ---- stage: 58368 B contiguous, wave-uniform LDS dest + lane*16 ----
    {
        const char* src = (const char*)(xb + (size_t)(b * XH + h0) * (XW * CINC));
        #pragma unroll
        for (int it = 0; it < 8; ++it) {
            int off = it * 8192 + wv * 1024;      // wave-uniform
            if (off < 4 * XW * CINC * 2) {
                gload16(src + off + lane * 16, ldsc + off);
            }
        }
    }
    __syncthreads();

    const int l16  = lane & 15;
    const int lhi  = lane >> 4;
    const int wm   = wv >> 2;         // cout group: [wm*64, wm*64+64)
    const int wn   = (wv >> 1) & 1;   // output row within pair
    const int ns   = wv & 1;          // n-half: 0 -> nf0..3, 1 -> nf0..2
    const int nfn  = 4 - ns;

    const u16* wrow = wbf + (wm * 64 + l16) * KTOT + lhi * 8;

    f32x4 acc[4][4];
    const f32x4 zero = {0.f, 0.f, 0.f, 0.f};
    #pragma unroll
    for (int i = 0; i < 4; ++i)
        #pragma unroll
        for (int j = 0; j < 4; ++j) acc[i][j] = zero;

    short8 aA0 = *(const short8*)(wrow);
    short8 aA1 = *(const short8*)(wrow + 16 * KTOT);
    short8 aA2 = *(const short8*)(wrow + 32 * KTOT);
    short8 aA3 = *(const short8*)(wrow + 48 * KTOT);
    short8 aB0, aB1, aB2, aB3;

    #pragma unroll 1
    for (int tt = 0; tt < 9; ++tt) {
        const int t0 = 2 * tt;
        aB0 = *(const short8*)(wrow + (t0 + 1) * 32);
        aB1 = *(const short8*)(wrow + 16 * KTOT + (t0 + 1) * 32);
        aB2 = *(const short8*)(wrow + 32 * KTOT + (t0 + 1) * 32);
        aB3 = *(const short8*)(wrow + 48 * KTOT + (t0 + 1) * 32);

        const int kh = tt / 3;
        const int kw = tt - kh * 3;
        const int r  = wn + kh;                 // input row offset in tile, 0..3
        const int hh2 = 2 * (h0 + r);           // for hash
        const int w0 = kw + ns * 64 + l16;

        { // ch=0: sigma = lhi
            #pragma unroll
            for (int nf = 0; nf < 4; ++nf) {
                if (nf >= nfn) break;
                const int w_ = w0 + nf * 16;
                const int pix = r * XW + w_;
                const int hash = (hh2 + w_) & 7;
                short8 bf = *(const short8*)(ldsc + (pix << 7) + ((lhi ^ hash) << 4));
                acc[0][nf] = MFMA16(aA0, bf, acc[0][nf]);
                acc[1][nf] = MFMA16(aA1, bf, acc[1][nf]);
                acc[2][nf] = MFMA16(aA2, bf, acc[2][nf]);
                acc[3][nf] = MFMA16(aA3, bf, acc[3][nf]);
            }
        }
        if (tt < 8) {
            aA0 = *(const short8*)(wrow + (t0 + 2) * 32);
            aA1 = *(const short8*)(wrow + 16 * KTOT + (t0 + 2) * 32);
            aA2 = *(const short8*)(wrow + 32 * KTOT + (t0 + 2) * 32);
            aA3 = *(const short8*)(wrow + 48 * KTOT + (t0 + 2) * 32);
        }
        { // ch=1: sigma = 4+lhi
            #pragma unroll
            for (int nf = 0; nf < 4; ++nf) {
                if (nf >= nfn) break;
                const int w_ = w0 + nf * 16;
                const int pix = r * XW + w_;
                const int hash = (hh2 + w_) & 7;
                short8 bf = *(const short8*)(ldsc + (pix << 7) + (((4 + lhi) ^ hash) << 4));
                acc[0][nf] = MFMA16(aB0, bf, acc[0][nf]);
                acc[1][nf] = MFMA16(aB1, bf, acc[1][nf]);
                acc[2][nf] = MFMA16(aB2, bf, acc[2][nf]);
                acc[3][nf] = MFMA16(aB3, bf, acc[3][nf]);
            }
        }
    }

    // ---- epilogue: C/D col=lane&15, row=(lane>>4)*4+j ----
    float* outb = out + (size_t)b * COUT * (OH * OW) + (h0 + wn) * OW + ns * 64;
    #pragma unroll
    for (int mf = 0; mf < 4; ++mf) {
        #pragma unroll
        for (int j = 0; j < 4; ++j) {
            const int o = wm * 64 + mf * 16 + lhi * 4 + j;
            const float bv = bias[o];
            #pragma unroll
            for (int nf = 0; nf < 4; ++nf) {
                if (nf >= nfn) break;
                outb[(size_t)o * (OH * OW) + nf * 16 + l16] = acc[mf][nf][j] + bv;
            }
        }
    }
}

// ---------------- fallback (R0 kernel, needs only 147456 B ws) ----------------

#define BK 32
#define NSTEP 18
#define LDB 40

__global__ __launch_bounds__(256) void wcvt_ident(const float* __restrict__ w,
                                                  u16* __restrict__ wbf) {
    int i = blockIdx.x * 256 + threadIdx.x;
    if (i < COUT * KTOT) wbf[i] = f2bf(w[i]);
}

__global__ __launch_bounds__(256) void conv_fb(const float* __restrict__ x,
                                               const u16* __restrict__ wbf,
                                               const float* __restrict__ bias,
                                               float* __restrict__ out) {
    __shared__ u16 ldsB[OW * LDB];
    const int tid = threadIdx.x;
    int bid = blockIdx.x;
    { int xcd = bid & 7; bid = xcd * 448 + (bid >> 3); }
    const int b = bid / OH;
    const int h = bid - b * OH;
    const float* xbp = x + (size_t)b * (CINC * XH * XW);
    float* outb = out + (size_t)b * (COUT * OH * OW) + h * OW;
    const int lane = tid & 63, wv = tid >> 6, l16 = lane & 15, lhi = lane >> 4;
    const int m0 = wv * 32;
    const int sk = tid >> 3, sn0 = (tid & 7) * 14;
    f32x4 acc[2][7];
    const f32x4 zero = {0.f, 0.f, 0.f, 0.f};
    #pragma unroll
    for (int i = 0; i < 2; ++i)
        #pragma unroll
        for (int j = 0; j < 7; ++j) acc[i][j] = zero;
    for (int t = 0; t < NSTEP; ++t) {
        const int kg = t * BK + sk;
        const int ci = kg / 9;
        const int r9 = kg - ci * 9;
        const int kh = r9 / 3, kw = r9 - (r9 / 3) * 3;
        const float* src = xbp + ((size_t)ci * XH + (h + kh)) * XW + kw + sn0;
        __syncthreads();
        #pragma unroll
        for (int i = 0; i < 14; ++i) ldsB[(sn0 + i) * LDB + sk] = f2bf(src[i]);
        __syncthreads();
        short8 afrag[2];
        #pragma unroll
        for (int mf = 0; mf < 2; ++mf)
            afrag[mf] = *(const short8*)(wbf + (m0 + mf * 16 + l16) * KTOT + t * BK + lhi * 8);
        #pragma unroll
        for (int nf = 0; nf < 7; ++nf) {
            short8 bfrag = *(const short8*)&ldsB[(nf * 16 + l16) * LDB + lhi * 8];
            acc[0][nf] = MFMA16(afrag[0], bfrag, acc[0][nf]);
            acc[1][nf] = MFMA16(afrag[1], bfrag, acc[1][nf]);
        }
    }
    #pragma unroll
    for (int mf = 0; mf < 2; ++mf)
        #pragma unroll
        for (int j = 0; j < 4; ++j) {
            const int o = m0 + mf * 16 + lhi * 4 + j;
            const float bv = bias[o];
            #pragma unroll
            for (int nf = 0; nf < 7; ++nf)
                outb[(size_t)o * (OH * OW) + nf * 16 + l16] = acc[mf][nf][j] + bv;
        }
}

extern "C" void kernel_launch(void* const* d_in, const int* in_sizes, int n_in,
                              void* d_out, int out_size, void* d_ws, size_t ws_size,
                              hipStream_t stream) {
    const float* x    = (const float*)d_in[0];
    const float* w    = (const float*)d_in[3];
    const float* bias = (const float*)d_in[4];
    float* out = (float*)d_out;

    const size_t WBYTES = (size_t)COUT * KTOT * 2;                 // 147456
    const size_t XBYTES = (size_t)NB * XH * XW * CINC * 2;         // 53231616
    if (ws_size >= WBYTES + XBYTES) {
        u16* wbf = (u16*)d_ws;
        u16* xb  = (u16*)((char*)d_ws + WBYTES);
        wcvt_reord<<<(COUT * KTOT) / 256, 256, 0, stream>>>(w, wbf);
        xcvt<<<NB * XH, 256, 0, stream>>>(x, xb);
        conv_glds<<<NB * 56, 512, 0, stream>>>(xb, wbf, bias, out);
    } else {
        u16* wbf = (u16*)d_ws;
        wcvt_ident<<<(COUT * KTOT + 255) / 256, 256, 0, stream>>>(w, wbf);
        conv_fb<<<NB * OH, 256, 0, stream>>>(x, wbf, bias, out);
    }
}

// Round 6
// 129.718 us; speedup vs baseline: 1.5013x; 1.3837x over previous
//
#include <hip/hip_runtime.h>

typedef __attribute__((ext_vector_type(8))) short short8;
typedef __attribute__((ext_vector_type(4))) float f32x4;
typedef __attribute__((ext_vector_type(4))) unsigned int u32x4;
typedef unsigned short u16;
typedef unsigned int u32;
typedef unsigned long long u64;

#define XH 114
#define XW 114
#define CINC 64
#define COUT 128
#define OH 112
#define OW 112
#define NB 32
#define KTOT 576   // CIN*9

static __device__ __forceinline__ u16 f2bf(float f) {
    u32 x = __float_as_uint(f);
    u32 r = (x + 0x7fffu + ((x >> 16) & 1u)) >> 16;
    return (u16)r;
}

#define MFMA16(a, b, c) __builtin_amdgcn_mfma_f32_16x16x32_bf16((a), (b), (c), 0, 0, 0)

static __device__ __forceinline__ void gload16(const void* g, void* l) {
    __builtin_amdgcn_global_load_lds(
        (const __attribute__((address_space(1))) unsigned int*)g,
        (__attribute__((address_space(3))) unsigned int*)l, 16, 0, 0);
}

// ---------------- fast path ----------------

// weights -> bf16, K reordered to (kh,kw,ci):  wbf[o][(kh*3+kw)*64 + ci]
__global__ __launch_bounds__(256) void wcvt_reord(const float* __restrict__ w,
                                                  u16* __restrict__ wbf) {
    int i = blockIdx.x * 256 + threadIdx.x;   // 73728 total, exact
    int o = i / KTOT;
    int rem = i - o * KTOT;
    int khkw = rem >> 6;        // 0..8
    int ci = rem & 63;
    wbf[i] = f2bf(w[(o * CINC + ci) * 9 + khkw]);
}

// x (NCHW f32, padded) -> xb bf16 with slot-swizzle BAKED into global layout:
//   xb[(b*114+h)*7296 + w*64 + (c8 ^ ((2h+w)&7))*8 + e] = x[b][8*c8+e][h][w]
__global__ __launch_bounds__(256) void xcvt(const float* __restrict__ x,
                                            u16* __restrict__ xb) {
    __shared__ u16 tile[XW * 70];   // [w][ci], u16 row stride 70 (dword 35, coprime 32)
    const int blk = blockIdx.x;     // 32*114
    const int b = blk / XH;
    const int h = blk - b * XH;
    const int tid = threadIdx.x;

    // phase 1: 3648 tasks = 32 ci-pairs x 114 w; coalesced f32 reads, packed u32 writes
    #pragma unroll
    for (int it = 0; it < 15; ++it) {
        int idx = it * 256 + tid;
        if (idx < 32 * XW) {
            int cp = idx / XW;                  // 0..31
            int w_ = idx - cp * XW;
            const float* s0 = x + ((size_t)(b * CINC + 2 * cp) * XH + h) * XW + w_;
            float a = s0[0];
            float c = s0[XH * XW];
            u32 pk = (u32)f2bf(a) | ((u32)f2bf(c) << 16);
            *(u32*)&tile[w_ * 70 + 2 * cp] = pk;
        }
    }
    __syncthreads();

    // phase 2: 912 tasks = 114 w x 8 c8; 4x ds_read_b32 -> one 16B store at swizzled slot
    u16* dstrow = xb + (size_t)(b * XH + h) * (XW * CINC);
    #pragma unroll
    for (int p2 = 0; p2 < 4; ++p2) {
        int task = p2 * 256 + tid;
        if (task < XW * 8) {
            int w_ = task >> 3;
            int c8 = task & 7;
            const u32* s = (const u32*)&tile[w_ * 70 + c8 * 8];
            u32x4 v = {s[0], s[1], s[2], s[3]};
            int slot = c8 ^ ((2 * h + w_) & 7);
            *(u32x4*)(dstrow + w_ * CINC + slot * 8) = v;
        }
    }
}

// implicit-GEMM conv: block=(b,row-pair), 512 thr = 8 waves (4 wm-groups x 2 rows).
// mf=2, nf=7: each A-frag (from L2) feeds 7 MFMAs; B from LDS, conflict-free.
// Staging = pure linear global_load_lds (swizzle pre-baked in xb).
__global__ __launch_bounds__(512, 4) void conv_r5(const u16* __restrict__ xb,
                                                  const u16* __restrict__ wbf,
                                                  const float* __restrict__ bias,
                                                  float* __restrict__ out) {
    __shared__ u16 ldsB[4 * XW * CINC];   // 58368 B, linear copy of 4 xb rows
    char* ldsc = (char*)ldsB;

    const int tid = threadIdx.x;
    int bid = blockIdx.x;
    { // bijective XCD swizzle: 1792 = 8*224
        int xcd = bid & 7;
        bid = xcd * 224 + (bid >> 3);
    }
    const int b  = bid / 56;
    const int h0 = (bid - b * 56) * 2;

    const int lane = tid & 63;
    const int wv   = tid >> 6;        // 0..7

    // ---- stage: 58368 B contiguous, wave-uniform LDS dest + lane*16 ----
    {
        const char* src = (const char*)(xb + (size_t)(b * XH + h0) * (XW * CINC));
        #pragma unroll
        for (int it = 0; it < 8; ++it) {
            int off = it * 8192 + wv * 1024;      // wave-uniform
            if (off < 4 * XW * CINC * 2) {
                gload16(src + off + lane * 16, ldsc + off);
            }
        }
    }
    __syncthreads();

    const int l16  = lane & 15;
    const int lhi  = lane >> 4;
    const int wm   = wv & 3;          // cout group: [wm*32, wm*32+32)
    const int wn   = wv >> 2;         // output row within pair

    const u16* wrow0 = wbf + (wm * 32 + l16) * KTOT + lhi * 8;
    const u16* wrow1 = wrow0 + 16 * KTOT;

    f32x4 acc[2][7];
    const f32x4 zero = {0.f, 0.f, 0.f, 0.f};
    #pragma unroll
    for (int i = 0; i < 2; ++i)
        #pragma unroll
        for (int j = 0; j < 7; ++j) acc[i][j] = zero;

    short8 aA0 = *(const short8*)(wrow0);
    short8 aA1 = *(const short8*)(wrow1);
    short8 aB0, aB1;

    #pragma unroll 1
    for (int tt = 0; tt < 9; ++tt) {
        const int t0 = 2 * tt;
        // prefetch odd tstep's A (same khkw, ch=1)
        aB0 = *(const short8*)(wrow0 + (t0 + 1) * 32);
        aB1 = *(const short8*)(wrow1 + (t0 + 1) * 32);

        const int kh = tt / 3;
        const int kw = tt - kh * 3;
        const int r  = wn + kh;                       // tile row 0..3
        const int pix0 = r * XW + kw + l16;
        const int hash = (2 * (h0 + r) + kw + l16) & 7;   // nf-invariant (16&7==0)
        const int baddr0 = (pix0 << 7) + ((lhi ^ hash) << 4);

        { // ch=0
            __builtin_amdgcn_s_setprio(1);
            #pragma unroll
            for (int nf = 0; nf < 7; ++nf) {
                short8 bf = *(const short8*)(ldsc + baddr0 + nf * 2048);
                acc[0][nf] = MFMA16(aA0, bf, acc[0][nf]);
                acc[1][nf] = MFMA16(aA1, bf, acc[1][nf]);
            }
            __builtin_amdgcn_s_setprio(0);
        }
        // prefetch next even tstep's A
        if (tt < 8) {
            aA0 = *(const short8*)(wrow0 + (t0 + 2) * 32);
            aA1 = *(const short8*)(wrow1 + (t0 + 2) * 32);
        }
        { // ch=1: slot base 4+lhi -> XOR 0x40 on the byte address
            __builtin_amdgcn_s_setprio(1);
            #pragma unroll
            for (int nf = 0; nf < 7; ++nf) {
                short8 bf = *(const short8*)(ldsc + (baddr0 ^ 0x40) + nf * 2048);
                acc[0][nf] = MFMA16(aB0, bf, acc[0][nf]);
                acc[1][nf] = MFMA16(aB1, bf, acc[1][nf]);
            }
            __builtin_amdgcn_s_setprio(0);
        }
    }

    // ---- epilogue: C/D col=lane&15, row=(lane>>4)*4+j ----
    float* outb = out + (size_t)b * COUT * (OH * OW) + (h0 + wn) * OW;
    #pragma unroll
    for (int mf = 0; mf < 2; ++mf) {
        #pragma unroll
        for (int j = 0; j < 4; ++j) {
            const int o = wm * 32 + mf * 16 + lhi * 4 + j;
            const float bv = bias[o];
            #pragma unroll
            for (int nf = 0; nf < 7; ++nf) {
                outb[(size_t)o * (OH * OW) + nf * 16 + l16] = acc[mf][nf][j] + bv;
            }
        }
    }
}

// ---------------- fallback (R0 kernel, needs only 147456 B ws) ----------------

#define BK 32
#define NSTEP 18
#define LDB 40

__global__ __launch_bounds__(256) void wcvt_ident(const float* __restrict__ w,
                                                  u16* __restrict__ wbf) {
    int i = blockIdx.x * 256 + threadIdx.x;
    if (i < COUT * KTOT) wbf[i] = f2bf(w[i]);
}

__global__ __launch_bounds__(256) void conv_fb(const float* __restrict__ x,
                                               const u16* __restrict__ wbf,
                                               const float* __restrict__ bias,
                                               float* __restrict__ out) {
    __shared__ u16 ldsB[OW * LDB];
    const int tid = threadIdx.x;
    int bid = blockIdx.x;
    { int xcd = bid & 7; bid = xcd * 448 + (bid >> 3); }
    const int b = bid / OH;
    const int h = bid - b * OH;
    const float* xbp = x + (size_t)b * (CINC * XH * XW);
    float* outb = out + (size_t)b * (COUT * OH * OW) + h * OW;
    const int lane = tid & 63, wv = tid >> 6, l16 = lane & 15, lhi = lane >> 4;
    const int m0 = wv * 32;
    const int sk = tid >> 3, sn0 = (tid & 7) * 14;
    f32x4 acc[2][7];
    const f32x4 zero = {0.f, 0.f, 0.f, 0.f};
    #pragma unroll
    for (int i = 0; i < 2; ++i)
        #pragma unroll
        for (int j = 0; j < 7; ++j) acc[i][j] = zero;
    for (int t = 0; t < NSTEP; ++t) {
        const int kg = t * BK + sk;
        const int ci = kg / 9;
        const int r9 = kg - ci * 9;
        const int kh = r9 / 3, kw = r9 - (r9 / 3) * 3;
        const float* src = xbp + ((size_t)ci * XH + (h + kh)) * XW + kw + sn0;
        __syncthreads();
        #pragma unroll
        for (int i = 0; i < 14; ++i) ldsB[(sn0 + i) * LDB + sk] = f2bf(src[i]);
        __syncthreads();
        short8 afrag[2];
        #pragma unroll
        for (int mf = 0; mf < 2; ++mf)
            afrag[mf] = *(const short8*)(wbf + (m0 + mf * 16 + l16) * KTOT + t * BK + lhi * 8);
        #pragma unroll
        for (int nf = 0; nf < 7; ++nf) {
            short8 bfrag = *(const short8*)&ldsB[(nf * 16 + l16) * LDB + lhi * 8];
            acc[0][nf] = MFMA16(afrag[0], bfrag, acc[0][nf]);
            acc[1][nf] = MFMA16(afrag[1], bfrag, acc[1][nf]);
        }
    }
    #pragma unroll
    for (int mf = 0; mf < 2; ++mf)
        #pragma unroll
        for (int j = 0; j < 4; ++j) {
            const int o = m0 + mf * 16 + lhi * 4 + j;
            const float bv = bias[o];
            #pragma unroll
            for (int nf = 0; nf < 7; ++nf)
                outb[(size_t)o * (OH * OW) + nf * 16 + l16] = acc[mf][nf][j] + bv;
        }
}

extern "C" void kernel_launch(void* const* d_in, const int* in_sizes, int n_in,
                              void* d_out, int out_size, void* d_ws, size_t ws_size,
                              hipStream_t stream) {
    const float* x    = (const float*)d_in[0];
    const float* w    = (const float*)d_in[3];
    const float* bias = (const float*)d_in[4];
    float* out = (float*)d_out;

    const size_t WBYTES = (size_t)COUT * KTOT * 2;                 // 147456
    const size_t XBYTES = (size_t)NB * XH * XW * CINC * 2;         // 53231616
    if (ws_size >= WBYTES + XBYTES) {
        u16* wbf = (u16*)d_ws;
        u16* xb  = (u16*)((char*)d_ws + WBYTES);
        wcvt_reord<<<(COUT * KTOT) / 256, 256, 0, stream>>>(w, wbf);
        xcvt<<<NB * XH, 256, 0, stream>>>(x, xb);
        conv_r5<<<NB * 56, 512, 0, stream>>>(xb, wbf, bias, out);
    } else {
        u16* wbf = (u16*)d_ws;
        wcvt_ident<<<(COUT * KTOT + 255) / 256, 256, 0, stream>>>(w, wbf);
        conv_fb<<<NB * OH, 256, 0, stream>>>(x, wbf, bias, out);
    }
}

// Round 7
// 122.119 us; speedup vs baseline: 1.5947x; 1.0622x over previous
//
#include <hip/hip_runtime.h>

typedef __attribute__((ext_vector_type(8))) short short8;
typedef __attribute__((ext_vector_type(4))) float f32x4;
typedef __attribute__((ext_vector_type(4))) unsigned int u32x4;
typedef unsigned short u16;
typedef unsigned int u32;
typedef unsigned long long u64;

#define XH 114
#define XW 114
#define CINC 64
#define COUT 128
#define OH 112
#define OW 112
#define NB 32
#define KTOT 576   // CIN*9
#define TILEB 58368   // 4*114*64*2 bytes per B tile

static __device__ __forceinline__ u16 f2bf(float f) {
    u32 x = __float_as_uint(f);
    u32 r = (x + 0x7fffu + ((x >> 16) & 1u)) >> 16;
    return (u16)r;
}

#define MFMA16(a, b, c) __builtin_amdgcn_mfma_f32_16x16x32_bf16((a), (b), (c), 0, 0, 0)

static __device__ __forceinline__ void gload16(const void* g, void* l) {
    __builtin_amdgcn_global_load_lds(
        (const __attribute__((address_space(1))) unsigned int*)g,
        (__attribute__((address_space(3))) unsigned int*)l, 16, 0, 0);
}

// ---------------- fast path ----------------

// weights -> bf16, K reordered to (kh,kw,ci):  wbf[o][(kh*3+kw)*64 + ci]
__global__ __launch_bounds__(256) void wcvt_reord(const float* __restrict__ w,
                                                  u16* __restrict__ wbf) {
    int i = blockIdx.x * 256 + threadIdx.x;   // 73728 total, exact
    int o = i / KTOT;
    int rem = i - o * KTOT;
    int khkw = rem >> 6;        // 0..8
    int ci = rem & 63;
    wbf[i] = f2bf(w[(o * CINC + ci) * 9 + khkw]);
}

// x (NCHW f32, padded) -> xb bf16 with slot-swizzle BAKED into global layout:
//   xb[(b*114+h)*7296 + w*64 + (c8 ^ ((2h+w)&7))*8 + e] = x[b][8*c8+e][h][w]
__global__ __launch_bounds__(256) void xcvt(const float* __restrict__ x,
                                            u16* __restrict__ xb) {
    __shared__ u16 tile[XW * 70];   // [w][ci], u16 row stride 70 (dword 35, coprime 32)
    const int blk = blockIdx.x;     // 32*114
    const int b = blk / XH;
    const int h = blk - b * XH;
    const int tid = threadIdx.x;

    // phase 1: 3648 tasks = 32 ci-pairs x 114 w; coalesced f32 reads, packed u32 writes
    #pragma unroll
    for (int it = 0; it < 15; ++it) {
        int idx = it * 256 + tid;
        if (idx < 32 * XW) {
            int cp = idx / XW;                  // 0..31
            int w_ = idx - cp * XW;
            const float* s0 = x + ((size_t)(b * CINC + 2 * cp) * XH + h) * XW + w_;
            float a = s0[0];
            float c = s0[XH * XW];
            u32 pk = (u32)f2bf(a) | ((u32)f2bf(c) << 16);
            *(u32*)&tile[w_ * 70 + 2 * cp] = pk;
        }
    }
    __syncthreads();

    // phase 2: 912 tasks = 114 w x 8 c8; 4x ds_read_b32 -> one 16B store at swizzled slot
    u16* dstrow = xb + (size_t)(b * XH + h) * (XW * CINC);
    #pragma unroll
    for (int p2 = 0; p2 < 4; ++p2) {
        int task = p2 * 256 + tid;
        if (task < XW * 8) {
            int w_ = task >> 3;
            int c8 = task & 7;
            const u32* s = (const u32*)&tile[w_ * 70 + c8 * 8];
            u32x4 v = {s[0], s[1], s[2], s[3]};
            int slot = c8 ^ ((2 * h + w_) & 7);
            *(u32x4*)(dstrow + w_ * CINC + slot * 8) = v;
        }
    }
}

// Persistent implicit-GEMM conv: 256 blocks x 512 thr; each block owns 7
// row-pair tiles. A (weights) lives in registers for the whole kernel;
// B double-buffered in LDS via global_load_lds issued one tile ahead.
__global__ __launch_bounds__(512, 2) void conv_pers(const u16* __restrict__ xb,
                                                    const u16* __restrict__ wbf,
                                                    const float* __restrict__ bias,
                                                    float* __restrict__ out) {
    __shared__ u16 lds[2 * 4 * XW * CINC];   // 116736 B (two 58368 B tiles)
    char* ldsc = (char*)lds;

    const int tid  = threadIdx.x;
    const int lane = tid & 63;
    const int wv   = tid >> 6;        // 0..7
    const int l16  = lane & 15;
    const int lhi  = lane >> 4;
    const int wm   = wv & 3;          // cout group: [wm*32, wm*32+32)
    const int wn   = wv >> 2;         // output row within pair

    const int t0g = blockIdx.x * 7;   // this block's first global tile

    // ---- A prologue: 36 short8 = whole per-wave weight set, lives in VGPRs ----
    const u16* wrow0 = wbf + (wm * 32 + l16) * KTOT + lhi * 8;
    const u16* wrow1 = wrow0 + 16 * KTOT;
    short8 areg[18][2];
    #pragma unroll
    for (int t = 0; t < 18; ++t) {
        areg[t][0] = *(const short8*)(wrow0 + t * 32);
        areg[t][1] = *(const short8*)(wrow1 + t * 32);
    }

    // ---- stage tile 0 into buffer 0 ----
    {
        const char* src = (const char*)(xb + (size_t)((t0g / 56) * XH + (t0g % 56) * 2) * (XW * CINC));
        #pragma unroll
        for (int it = 0; it < 8; ++it) {
            int off = it * 8192 + wv * 1024;
            if (off < TILEB) gload16(src + off + lane * 16, ldsc + off);
        }
    }

    const f32x4 zero = {0.f, 0.f, 0.f, 0.f};

    #pragma unroll 1
    for (int i = 0; i < 7; ++i) {
        // drain: buf[i&1]'s staging complete; everyone done reading buf[1-(i&1)]
        __syncthreads();

        // issue next tile's staging into the other buffer (hidden under compute)
        if (i < 6) {
            const int tg = t0g + i + 1;
            const char* src = (const char*)(xb + (size_t)((tg / 56) * XH + (tg % 56) * 2) * (XW * CINC));
            char* dstb = ldsc + ((i + 1) & 1) * TILEB;
            #pragma unroll
            for (int it = 0; it < 8; ++it) {
                int off = it * 8192 + wv * 1024;
                if (off < TILEB) gload16(src + off + lane * 16, dstb + off);
            }
        }

        const int tg = t0g + i;
        const int b  = tg / 56;
        const int h0 = (tg - b * 56) * 2;
        char* buf = ldsc + (i & 1) * TILEB;

        f32x4 acc[2][7];
        #pragma unroll
        for (int mf = 0; mf < 2; ++mf)
            #pragma unroll
            for (int nf = 0; nf < 7; ++nf) acc[mf][nf] = zero;

        #pragma unroll
        for (int tt = 0; tt < 9; ++tt) {
            const int kh = tt / 3;
            const int kw = tt - kh * 3;
            const int r  = wn + kh;                        // tile row 0..3
            const int pix0 = r * XW + kw + l16;
            const int hash = (2 * (h0 + r) + kw + l16) & 7;   // nf-invariant
            const int ba0 = (pix0 << 7) + ((lhi ^ hash) << 4);

            __builtin_amdgcn_s_setprio(1);
            #pragma unroll
            for (int nf = 0; nf < 7; ++nf) {
                short8 bf = *(const short8*)(buf + ba0 + nf * 2048);
                acc[0][nf] = MFMA16(areg[2 * tt][0], bf, acc[0][nf]);
                acc[1][nf] = MFMA16(areg[2 * tt][1], bf, acc[1][nf]);
            }
            __builtin_amdgcn_s_setprio(0);

            __builtin_amdgcn_s_setprio(1);
            #pragma unroll
            for (int nf = 0; nf < 7; ++nf) {
                short8 bf = *(const short8*)(buf + (ba0 ^ 0x40) + nf * 2048);
                acc[0][nf] = MFMA16(areg[2 * tt + 1][0], bf, acc[0][nf]);
                acc[1][nf] = MFMA16(areg[2 * tt + 1][1], bf, acc[1][nf]);
            }
            __builtin_amdgcn_s_setprio(0);
        }

        // ---- epilogue: C/D col=lane&15, row=(lane>>4)*4+j ----
        float* outb = out + (size_t)b * COUT * (OH * OW) + (h0 + wn) * OW;
        #pragma unroll
        for (int mf = 0; mf < 2; ++mf) {
            #pragma unroll
            for (int j = 0; j < 4; ++j) {
                const int o = wm * 32 + mf * 16 + lhi * 4 + j;
                const float bv = bias[o];
                #pragma unroll
                for (int nf = 0; nf < 7; ++nf) {
                    outb[(size_t)o * (OH * OW) + nf * 16 + l16] = acc[mf][nf][j] + bv;
                }
            }
        }
    }
}

// ---------------- fallback (R0 kernel, needs only 147456 B ws) ----------------

#define BK 32
#define NSTEP 18
#define LDB 40

__global__ __launch_bounds__(256) void wcvt_ident(const float* __restrict__ w,
                                                  u16* __restrict__ wbf) {
    int i = blockIdx.x * 256 + threadIdx.x;
    if (i < COUT * KTOT) wbf[i] = f2bf(w[i]);
}

__global__ __launch_bounds__(256) void conv_fb(const float* __restrict__ x,
                                               const u16* __restrict__ wbf,
                                               const float* __restrict__ bias,
                                               float* __restrict__ out) {
    __shared__ u16 ldsB[OW * LDB];
    const int tid = threadIdx.x;
    int bid = blockIdx.x;
    { int xcd = bid & 7; bid = xcd * 448 + (bid >> 3); }
    const int b = bid / OH;
    const int h = bid - b * OH;
    const float* xbp = x + (size_t)b * (CINC * XH * XW);
    float* outb = out + (size_t)b * (COUT * OH * OW) + h * OW;
    const int lane = tid & 63, wv = tid >> 6, l16 = lane & 15, lhi = lane >> 4;
    const int m0 = wv * 32;
    const int sk = tid >> 3, sn0 = (tid & 7) * 14;
    f32x4 acc[2][7];
    const f32x4 zero = {0.f, 0.f, 0.f, 0.f};
    #pragma unroll
    for (int i = 0; i < 2; ++i)
        #pragma unroll
        for (int j = 0; j < 7; ++j) acc[i][j] = zero;
    for (int t = 0; t < NSTEP; ++t) {
        const int kg = t * BK + sk;
        const int ci = kg / 9;
        const int r9 = kg - ci * 9;
        const int kh = r9 / 3, kw = r9 - (r9 / 3) * 3;
        const float* src = xbp + ((size_t)ci * XH + (h + kh)) * XW + kw + sn0;
        __syncthreads();
        #pragma unroll
        for (int i = 0; i < 14; ++i) ldsB[(sn0 + i) * LDB + sk] = f2bf(src[i]);
        __syncthreads();
        short8 afrag[2];
        #pragma unroll
        for (int mf = 0; mf < 2; ++mf)
            afrag[mf] = *(const short8*)(wbf + (m0 + mf * 16 + l16) * KTOT + t * BK + lhi * 8);
        #pragma unroll
        for (int nf = 0; nf < 7; ++nf) {
            short8 bfrag = *(const short8*)&ldsB[(nf * 16 + l16) * LDB + lhi * 8];
            acc[0][nf] = MFMA16(afrag[0], bfrag, acc[0][nf]);
            acc[1][nf] = MFMA16(afrag[1], bfrag, acc[1][nf]);
        }
    }
    #pragma unroll
    for (int mf = 0; mf < 2; ++mf)
        #pragma unroll
        for (int j = 0; j < 4; ++j) {
            const int o = m0 + mf * 16 + lhi * 4 + j;
            const float bv = bias[o];
            #pragma unroll
            for (int nf = 0; nf < 7; ++nf)
                outb[(size_t)o * (OH * OW) + nf * 16 + l16] = acc[mf][nf][j] + bv;
        }
}

extern "C" void kernel_launch(void* const* d_in, const int* in_sizes, int n_in,
                              void* d_out, int out_size, void* d_ws, size_t ws_size,
                              hipStream_t stream) {
    const float* x    = (const float*)d_in[0];
    const float* w    = (const float*)d_in[3];
    const float* bias = (const float*)d_in[4];
    float* out = (float*)d_out;

    const size_t WBYTES = (size_t)COUT * KTOT * 2;                 // 147456
    const size_t XBYTES = (size_t)NB * XH * XW * CINC * 2;         // 53231616
    if (ws_size >= WBYTES + XBYTES) {
        u16* wbf = (u16*)d_ws;
        u16* xb  = (u16*)((char*)d_ws + WBYTES);
        wcvt_reord<<<(COUT * KTOT) / 256, 256, 0, stream>>>(w, wbf);
        xcvt<<<NB * XH, 256, 0, stream>>>(x, xb);
        conv_pers<<<256, 512, 0, stream>>>(xb, wbf, bias, out);
    } else {
        u16* wbf = (u16*)d_ws;
        wcvt_ident<<<(COUT * KTOT + 255) / 256, 256, 0, stream>>>(w, wbf);
        conv_fb<<<NB * OH, 256, 0, stream>>>(x, wbf, bias, out);
    }
}